// Round 1
// baseline (511.264 us; speedup 1.0000x reference)
//
#include <hip/hip_runtime.h>
#include <hip/hip_bf16.h>
#include <stdint.h>

#define B_ 4
#define T_ 2048
#define D_ 1024
#define H_ 16
#define HD_ 64
#define M_ (B_*T_)    // 8192
#define N1_ (3*D_)    // 3072

typedef __attribute__((ext_vector_type(8))) short short8;
typedef __attribute__((ext_vector_type(4))) float f32x4;

typedef const __attribute__((address_space(1))) void* as1cp;
typedef __attribute__((address_space(3))) void* as3p;

__device__ __forceinline__ ushort f2bf(float f) {
  union { float f; unsigned u; } v; v.f = f;
  unsigned r = v.u + 0x7fffu + ((v.u >> 16) & 1u);
  return (ushort)(r >> 16);
}

__global__ void cast_f32_bf16(const float* __restrict__ in, ushort* __restrict__ out, int n4) {
  int i = blockIdx.x * blockDim.x + threadIdx.x;
  int stride = gridDim.x * blockDim.x;
  for (; i < n4; i += stride) {
    float4 v = reinterpret_cast<const float4*>(in)[i];
    ushort4 o;
    o.x = f2bf(v.x); o.y = f2bf(v.y); o.z = f2bf(v.z); o.w = f2bf(v.w);
    reinterpret_cast<ushort4*>(out)[i] = o;
  }
}

__device__ __forceinline__ void gload_lds16(const ushort* g, ushort* l) {
  __builtin_amdgcn_global_load_lds((as1cp)(const void*)g, (as3p)(void*)l, 16, 0, 0);
}

// C[M,N] = A[M,K] * B[N,K]^T, all bf16 in, fp32 accum.
// 128x128 tile, BK=32, 4 waves (2x2), each wave 64x64 (4x4 frags of 16x16x32).
template<int OUT_BF16>
__global__ __launch_bounds__(256) void gemm_bt(const ushort* __restrict__ A,
                                               const ushort* __restrict__ Bm,
                                               void* __restrict__ Cout,
                                               int M, int N, int K) {
  __shared__ ushort Al[128*32];
  __shared__ ushort Bl[128*32];
  const int tid  = threadIdx.x;
  const int lane = tid & 63;
  const int w    = tid >> 6;
  const int g    = lane >> 4;
  const int ln   = lane & 15;
  const int m0 = blockIdx.y * 128;
  const int n0 = blockIdx.x * 128;
  const int wr = w >> 1, wc = w & 1;

  f32x4 acc[4][4] = {};

  for (int kt = 0; kt < K; kt += 32) {
    __syncthreads();
    #pragma unroll
    for (int j = 0; j < 2; ++j) {
      int cc  = w * 2 + j;           // chunk 0..7 (wave-uniform)
      int idx = cc * 64 + lane;
      int row = idx >> 2;
      int kofs = (idx & 3) * 8;
      gload_lds16(A  + (size_t)(m0 + row) * K + kt + kofs, &Al[cc * 512]);
      gload_lds16(Bm + (size_t)(n0 + row) * K + kt + kofs, &Bl[cc * 512]);
    }
    __syncthreads();
    short8 a[4], b[4];
    #pragma unroll
    for (int m = 0; m < 4; ++m)
      a[m] = *(const short8*)&Al[(wr*64 + m*16 + ln) * 32 + g*8];
    #pragma unroll
    for (int n = 0; n < 4; ++n)
      b[n] = *(const short8*)&Bl[(wc*64 + n*16 + ln) * 32 + g*8];
    #pragma unroll
    for (int m = 0; m < 4; ++m)
      #pragma unroll
      for (int n = 0; n < 4; ++n)
        acc[m][n] = __builtin_amdgcn_mfma_f32_16x16x32_bf16(a[m], b[n], acc[m][n], 0, 0, 0);
  }

  #pragma unroll
  for (int m = 0; m < 4; ++m) {
    int gr = m0 + wr*64 + m*16 + g*4;
    #pragma unroll
    for (int n = 0; n < 4; ++n) {
      int gc = n0 + wc*64 + n*16 + ln;
      #pragma unroll
      for (int r = 0; r < 4; ++r) {
        if (OUT_BF16) ((ushort*)Cout)[(size_t)(gr + r) * N + gc] = f2bf(acc[m][n][r]);
        else          ((float*)Cout)[(size_t)(gr + r) * N + gc]  = acc[m][n][r];
      }
    }
  }
}

// Flash attention, causal. qkv rows: [q(1024) | k(1024) | v(1024)] bf16.
// Block = 4 waves; wave w owns q rows q0..q0+15; 32-key tiles staged in LDS.
__global__ __launch_bounds__(256) void attn_kernel(const ushort* __restrict__ qkv,
                                                   ushort* __restrict__ y) {
  __shared__ ushort Kl[32][72];       // keys x d, padded (+8) -> 2-way banks
  __shared__ ushort Vt[64][40];       // d x keys (transposed), padded
  __shared__ ushort Pl[4][16][40];    // per-wave P staging, padded

  const int tid  = threadIdx.x;
  const int lane = tid & 63;
  const int wave = tid >> 6;
  const int g    = lane >> 4;
  const int ln   = lane & 15;

  const int qblock = blockIdx.x;
  const int bh = blockIdx.y;
  const int b  = bh >> 4;             // H=16
  const int h  = bh & 15;
  const int rowbase = b * T_;
  const int q0 = qblock * 64 + wave * 16;

  short8 qf[2];
  {
    const ushort* qp = qkv + (size_t)(rowbase + q0 + ln) * N1_ + h * HD_;
    qf[0] = *(const short8*)(qp + 0*32 + g*8);
    qf[1] = *(const short8*)(qp + 1*32 + g*8);
  }

  float mrun[4], lrun[4];
  f32x4 o[4] = {};
  #pragma unroll
  for (int r = 0; r < 4; ++r) { mrun[r] = -3.0e38f; lrun[r] = 0.f; }

  const int numTiles = qblock * 2 + 2;
  const int srow  = tid >> 3;         // 0..31
  const int sdofs = (tid & 7) * 8;    // 0..56

  for (int kt = 0; kt < numTiles; ++kt) {
    const int kbase = kt * 32;
    __syncthreads();
    {
      const size_t rb = (size_t)(rowbase + kbase + srow) * N1_ + h * HD_ + sdofs;
      short8 kvv = *(const short8*)(qkv + rb + D_);
      *(short8*)&Kl[srow][sdofs] = kvv;
      short8 vvv = *(const short8*)(qkv + rb + 2*D_);
      #pragma unroll
      for (int j = 0; j < 8; ++j) Vt[sdofs + j][srow] = (ushort)vvv[j];
    }
    __syncthreads();
    if (kbase <= q0 + 15) {
      f32x4 s0 = {}, s1 = {};
      #pragma unroll
      for (int half = 0; half < 2; ++half) {
        short8 k0 = *(const short8*)&Kl[ln][half*32 + g*8];
        short8 k1 = *(const short8*)&Kl[16 + ln][half*32 + g*8];
        s0 = __builtin_amdgcn_mfma_f32_16x16x32_bf16(qf[half], k0, s0, 0, 0, 0);
        s1 = __builtin_amdgcn_mfma_f32_16x16x32_bf16(qf[half], k1, s1, 0, 0, 0);
      }
      float p0[4], p1[4];
      #pragma unroll
      for (int r = 0; r < 4; ++r) {
        int qrow = q0 + g*4 + r;
        float a0 = s0[r] * 0.125f;
        float a1 = s1[r] * 0.125f;
        if (kbase + ln > qrow)       a0 = -3.0e38f;
        if (kbase + 16 + ln > qrow)  a1 = -3.0e38f;
        float mx = fmaxf(a0, a1);
        mx = fmaxf(mx, __shfl_xor(mx, 1));
        mx = fmaxf(mx, __shfl_xor(mx, 2));
        mx = fmaxf(mx, __shfl_xor(mx, 4));
        mx = fmaxf(mx, __shfl_xor(mx, 8));
        float mnew = fmaxf(mrun[r], mx);
        float alpha = __expf(mrun[r] - mnew);
        mrun[r] = mnew;
        float e0 = __expf(a0 - mnew);
        float e1 = __expf(a1 - mnew);
        float rs = e0 + e1;
        rs += __shfl_xor(rs, 1);
        rs += __shfl_xor(rs, 2);
        rs += __shfl_xor(rs, 4);
        rs += __shfl_xor(rs, 8);
        lrun[r] = lrun[r] * alpha + rs;
        #pragma unroll
        for (int t2 = 0; t2 < 4; ++t2) o[t2][r] *= alpha;
        p0[r] = e0; p1[r] = e1;
      }
      #pragma unroll
      for (int r = 0; r < 4; ++r) {
        Pl[wave][g*4 + r][ln]      = f2bf(p0[r]);
        Pl[wave][g*4 + r][16 + ln] = f2bf(p1[r]);
      }
      asm volatile("s_waitcnt lgkmcnt(0)" ::: "memory");
      short8 pa = *(const short8*)&Pl[wave][ln][g*8];
      #pragma unroll
      for (int t2 = 0; t2 < 4; ++t2) {
        short8 vf = *(const short8*)&Vt[t2*16 + ln][g*8];
        o[t2] = __builtin_amdgcn_mfma_f32_16x16x32_bf16(pa, vf, o[t2], 0, 0, 0);
      }
    }
  }

  #pragma unroll
  for (int t2 = 0; t2 < 4; ++t2) {
    #pragma unroll
    for (int r = 0; r < 4; ++r) {
      float val = o[t2][r] / lrun[r];
      int row = rowbase + q0 + g*4 + r;
      int col = h * HD_ + t2*16 + ln;
      y[(size_t)row * D_ + col] = f2bf(val);
    }
  }
}

extern "C" void kernel_launch(void* const* d_in, const int* in_sizes, int n_in,
                              void* d_out, int out_size, void* d_ws, size_t ws_size,
                              hipStream_t stream) {
  const float* x    = (const float*)d_in[0];
  const float* Wqkv = (const float*)d_in[1];
  const float* Wout = (const float*)d_in[2];

  ushort* xb    = (ushort*)d_ws;
  ushort* wqkvb = xb    + (size_t)M_ * D_;     // 8192*1024
  ushort* woutb = wqkvb + (size_t)N1_ * D_;    // 3072*1024
  ushort* qkvb  = woutb + (size_t)D_ * D_;     // 1024*1024
  ushort* yb    = qkvb  + (size_t)M_ * N1_;    // 8192*3072

  cast_f32_bf16<<<1024, 256, 0, stream>>>(x,    xb,    M_ * D_ / 4);
  cast_f32_bf16<<<512,  256, 0, stream>>>(Wqkv, wqkvb, N1_ * D_ / 4);
  cast_f32_bf16<<<256,  256, 0, stream>>>(Wout, woutb, D_ * D_ / 4);

  gemm_bt<1><<<dim3(N1_/128, M_/128), 256, 0, stream>>>(xb, wqkvb, qkvb, M_, N1_, D_);

  attn_kernel<<<dim3(T_/64, B_*H_), 256, 0, stream>>>(qkvb, yb);

  gemm_bt<0><<<dim3(D_/128, M_/128), 256, 0, stream>>>(yb, woutb, d_out, M_, D_, D_);
}

// Round 2
// 455.552 us; speedup vs baseline: 1.1223x; 1.1223x over previous
//
#include <hip/hip_runtime.h>
#include <hip/hip_bf16.h>
#include <stdint.h>

#define B_ 4
#define T_ 2048
#define D_ 1024
#define H_ 16
#define M_ (B_*T_)    // 8192
#define N1_ (3*D_)    // 3072

typedef __attribute__((ext_vector_type(8))) short short8;
typedef __attribute__((ext_vector_type(4))) short short4v;
typedef __attribute__((ext_vector_type(4))) float f32x4;

typedef const __attribute__((address_space(1))) void* as1cp;
typedef __attribute__((address_space(3))) void* as3p;

__device__ __forceinline__ ushort f2bf(float f) {
  union { float f; unsigned u; } v; v.f = f;
  unsigned r = v.u + 0x7fffu + ((v.u >> 16) & 1u);
  return (ushort)(r >> 16);
}

__global__ void cast_f32_bf16(const float* __restrict__ in, ushort* __restrict__ out, int n4) {
  int i = blockIdx.x * blockDim.x + threadIdx.x;
  int stride = gridDim.x * blockDim.x;
  for (; i < n4; i += stride) {
    float4 v = reinterpret_cast<const float4*>(in)[i];
    ushort4 o;
    o.x = f2bf(v.x); o.y = f2bf(v.y); o.z = f2bf(v.z); o.w = f2bf(v.w);
    reinterpret_cast<ushort4*>(out)[i] = o;
  }
}

__device__ __forceinline__ void gload_lds16(const ushort* g, ushort* l) {
  __builtin_amdgcn_global_load_lds((as1cp)(const void*)g, (as3p)(void*)l, 16, 0, 0);
}

__device__ __forceinline__ short4v ds_tr16(unsigned addr) {
  short4v r;
  asm volatile("ds_read_b64_tr_b16 %0, %1" : "=v"(r) : "v"(addr) : "memory");
  return r;
}

__device__ __forceinline__ short8 cat8(short4v a, short4v b) {
  short8 r;
  r[0]=a[0]; r[1]=a[1]; r[2]=a[2]; r[3]=a[3];
  r[4]=b[0]; r[5]=b[1]; r[6]=b[2]; r[7]=b[3];
  return r;
}

// ---------------- GEMM (unchanged from round 0, passed) ----------------
template<int OUT_BF16>
__global__ __launch_bounds__(256) void gemm_bt(const ushort* __restrict__ A,
                                               const ushort* __restrict__ Bm,
                                               void* __restrict__ Cout,
                                               int M, int N, int K) {
  __shared__ ushort Al[128*32];
  __shared__ ushort Bl[128*32];
  const int tid  = threadIdx.x;
  const int lane = tid & 63;
  const int w    = tid >> 6;
  const int g    = lane >> 4;
  const int ln   = lane & 15;
  const int m0 = blockIdx.y * 128;
  const int n0 = blockIdx.x * 128;
  const int wr = w >> 1, wc = w & 1;

  f32x4 acc[4][4] = {};

  for (int kt = 0; kt < K; kt += 32) {
    __syncthreads();
    #pragma unroll
    for (int j = 0; j < 2; ++j) {
      int cc  = w * 2 + j;
      int idx = cc * 64 + lane;
      int row = idx >> 2;
      int kofs = (idx & 3) * 8;
      gload_lds16(A  + (size_t)(m0 + row) * K + kt + kofs, &Al[cc * 512]);
      gload_lds16(Bm + (size_t)(n0 + row) * K + kt + kofs, &Bl[cc * 512]);
    }
    __syncthreads();
    short8 a[4], b[4];
    #pragma unroll
    for (int m = 0; m < 4; ++m)
      a[m] = *(const short8*)&Al[(wr*64 + m*16 + ln) * 32 + g*8];
    #pragma unroll
    for (int n = 0; n < 4; ++n)
      b[n] = *(const short8*)&Bl[(wc*64 + n*16 + ln) * 32 + g*8];
    #pragma unroll
    for (int m = 0; m < 4; ++m)
      #pragma unroll
      for (int n = 0; n < 4; ++n)
        acc[m][n] = __builtin_amdgcn_mfma_f32_16x16x32_bf16(a[m], b[n], acc[m][n], 0, 0, 0);
  }

  #pragma unroll
  for (int m = 0; m < 4; ++m) {
    int gr = m0 + wr*64 + m*16 + g*4;
    #pragma unroll
    for (int n = 0; n < 4; ++n) {
      int gc = n0 + wc*64 + n*16 + ln;
      #pragma unroll
      for (int r = 0; r < 4; ++r) {
        if (OUT_BF16) ((ushort*)Cout)[(size_t)(gr + r) * N + gc] = f2bf(acc[m][n][r]);
        else          ((float*)Cout)[(size_t)(gr + r) * N + gc]  = acc[m][n][r];
      }
    }
  }
}

// ---------------- Flash attention v2 ----------------
// Block: 4 waves, 128 q-rows (wave w owns rows m*64+w*16, m=0..1). KV tile 64.
// K: linear LDS [64][64], XOR-swizzled content via pre-swizzled global src.
// V: subtiled [kg=key/4][c=d/16][4][16] for ds_read_b64_tr_b16.
// P: written as P^T subtiled [kg][qc][4key][16q], read back via tr_b16.
__global__ __launch_bounds__(256) void attn2(const ushort* __restrict__ qkv,
                                             ushort* __restrict__ y) {
  __shared__ ushort Kl[64*64];        // 8 KB
  __shared__ ushort Vl[64*64];        // 8 KB
  __shared__ ushort Pl[4][2048];      // 16 KB (4 KB / wave)

  const int tid  = threadIdx.x;
  const int lane = tid & 63;
  const int w    = tid >> 6;
  const int g    = lane >> 4;
  const int ln   = lane & 15;

  const int bh = blockIdx.y;
  const int b  = bh >> 4;
  const int h  = bh & 15;
  const int rowg = b * T_;
  const int qb = (int)(gridDim.x - 1 - blockIdx.x);  // heavy blocks first
  const int q0 = qb * 128;

  // Q fragments: qf[m][kf], A-frag row ln = q row q0+m*64+w*16+ln
  short8 qf[2][2];
  #pragma unroll
  for (int m = 0; m < 2; ++m) {
    const ushort* qp = qkv + (size_t)(rowg + q0 + m*64 + w*16 + ln) * N1_ + h*64;
    #pragma unroll
    for (int kf = 0; kf < 2; ++kf)
      qf[m][kf] = *(const short8*)(qp + kf*32 + g*8);
  }

  float mr[2][4], lr[2][4];
  f32x4 o[2][4] = {};
  #pragma unroll
  for (int m = 0; m < 2; ++m)
    #pragma unroll
    for (int r = 0; r < 4; ++r) { mr[m][r] = -3.0e38f; lr[m][r] = 0.f; }

  const unsigned VlB = (unsigned)(size_t)(as3p)(void*)&Vl[0];
  const unsigned PlB = (unsigned)(size_t)(as3p)(void*)&Pl[w][0];

  // Hoistable tr-read addresses (lane-constant across tiles)
  // V: tile s=(kf*8+2g)*4+t2, addr = s*128 + ln*8 ; second read +512B
  // P: tile s=kf*16+4g+m,     addr = s*128 + ln*8 ; second read +256B

  const int nt = qb*2 + 2;
  for (int kt = 0; kt < nt; ++kt) {
    const int kbase = kt * 64;
    __syncthreads();
    // ---- stage K (pre-swizzled source -> linear LDS; read-side XOR-swizzle) ----
    #pragma unroll
    for (int i = 0; i < 2; ++i) {
      int rl = w*16 + i*8 + (lane >> 3);
      int cb = ((lane & 7) * 16) ^ ((rl & 7) << 4);   // byte offset in row
      gload_lds16(qkv + (size_t)(rowg + kbase + rl) * N1_ + D_ + h*64 + (cb >> 1),
                  &Kl[(w*2 + i) * 512]);
    }
    // ---- stage V (pre-permuted source -> linear LDS = subtiled layout) ----
    #pragma unroll
    for (int i = 0; i < 2; ++i) {
      int s   = (w*2 + i)*8 + (lane >> 3);   // subtile index
      int r   = (lane >> 1) & 3;
      int e0  = (lane & 1) * 8;
      int key = (s >> 2) * 4 + r;
      int d   = (s & 3) * 16 + e0;
      gload_lds16(qkv + (size_t)(rowg + kbase + key) * N1_ + 2*D_ + h*64 + d,
                  &Vl[(w*2 + i) * 512]);
    }
    __syncthreads();

    const bool act[2] = { kbase <= q0 + 0*64 + w*16 + 15,
                          kbase <= q0 + 1*64 + w*16 + 15 };

    #pragma unroll
    for (int m = 0; m < 2; ++m) {
      if (!act[m]) continue;
      const int rb = q0 + m*64 + w*16;
      // ---- QK^T ----
      f32x4 sc[4] = {};
      #pragma unroll
      for (int kf = 0; kf < 2; ++kf) {
        #pragma unroll
        for (int n = 0; n < 4; ++n) {
          unsigned boff = (unsigned)((n*16 + ln) * 128)
                        + ((unsigned)(kf*64 + g*16) ^ ((unsigned)(ln & 7) << 4));
          short8 bfr = *(const short8*)((const char*)Kl + boff);
          sc[n] = __builtin_amdgcn_mfma_f32_16x16x32_bf16(qf[m][kf], bfr, sc[n], 0, 0, 0);
        }
      }
      // ---- softmax (log2 domain) ----
      const float Cs = 0.125f * 1.44269504f;
      const bool diag = (kbase + 63 > rb);
      float ev[4][4];
      float alpha[4];
      #pragma unroll
      for (int r = 0; r < 4; ++r) {
        float a0 = sc[0][r]*Cs, a1 = sc[1][r]*Cs, a2 = sc[2][r]*Cs, a3 = sc[3][r]*Cs;
        if (diag) {
          int qrow = rb + g*4 + r;
          if (kbase +  0 + ln > qrow) a0 = -3.0e38f;
          if (kbase + 16 + ln > qrow) a1 = -3.0e38f;
          if (kbase + 32 + ln > qrow) a2 = -3.0e38f;
          if (kbase + 48 + ln > qrow) a3 = -3.0e38f;
        }
        float mx = fmaxf(fmaxf(a0, a1), fmaxf(a2, a3));
        mx = fmaxf(mx, __shfl_xor(mx, 1));
        mx = fmaxf(mx, __shfl_xor(mx, 2));
        mx = fmaxf(mx, __shfl_xor(mx, 4));
        mx = fmaxf(mx, __shfl_xor(mx, 8));
        float mn = fmaxf(mr[m][r], mx);
        alpha[r] = exp2f(mr[m][r] - mn);
        mr[m][r] = mn;
        float e0 = exp2f(a0 - mn);
        float e1 = exp2f(a1 - mn);
        float e2 = exp2f(a2 - mn);
        float e3 = exp2f(a3 - mn);
        if (diag) {
          e0 = (a0 <= -1.0e37f) ? 0.f : e0;
          e1 = (a1 <= -1.0e37f) ? 0.f : e1;
          e2 = (a2 <= -1.0e37f) ? 0.f : e2;
          e3 = (a3 <= -1.0e37f) ? 0.f : e3;
        }
        float rs = (e0 + e1) + (e2 + e3);
        rs += __shfl_xor(rs, 1);
        rs += __shfl_xor(rs, 2);
        rs += __shfl_xor(rs, 4);
        rs += __shfl_xor(rs, 8);
        lr[m][r] = lr[m][r] * alpha[r] + rs;
        ev[0][r] = e0; ev[1][r] = e1; ev[2][r] = e2; ev[3][r] = e3;
      }
      // rescale accumulator
      #pragma unroll
      for (int t2 = 0; t2 < 4; ++t2)
        #pragma unroll
        for (int r = 0; r < 4; ++r) o[m][t2][r] *= alpha[r];
      // ---- write P^T (packed b64: 4 q-rows per write) ----
      #pragma unroll
      for (int n = 0; n < 4; ++n) {
        short4v pk;
        pk[0] = (short)f2bf(ev[n][0]);
        pk[1] = (short)f2bf(ev[n][1]);
        pk[2] = (short)f2bf(ev[n][2]);
        pk[3] = (short)f2bf(ev[n][3]);
        int sw = (4*n + (ln >> 2)) * 2 + m;   // subtile: kg*2 + qc
        *(short4v*)&Pl[w][sw*64 + (ln & 3)*16 + g*4] = pk;
      }
    }

    // ---- PV via hardware transpose reads ----
    asm volatile("s_waitcnt lgkmcnt(0)" ::: "memory");
    short4v vfr[4][2][2];
    #pragma unroll
    for (int t2 = 0; t2 < 4; ++t2)
      #pragma unroll
      for (int kf = 0; kf < 2; ++kf) {
        unsigned a = VlB + (unsigned)(kf*4096 + g*1024 + t2*128 + ln*8);
        vfr[t2][kf][0] = ds_tr16(a);
        vfr[t2][kf][1] = ds_tr16(a + 512);
      }
    short4v pfr[2][2][2];
    #pragma unroll
    for (int m = 0; m < 2; ++m) {
      if (!act[m]) continue;
      #pragma unroll
      for (int kf = 0; kf < 2; ++kf) {
        unsigned a = PlB + (unsigned)((kf*16 + 4*g + m)*128 + ln*8);
        pfr[m][kf][0] = ds_tr16(a);
        pfr[m][kf][1] = ds_tr16(a + 256);
      }
    }
    asm volatile("s_waitcnt lgkmcnt(0)" ::: "memory");
    __builtin_amdgcn_sched_barrier(0);
    #pragma unroll
    for (int m = 0; m < 2; ++m) {
      if (!act[m]) continue;
      #pragma unroll
      for (int t2 = 0; t2 < 4; ++t2) {
        #pragma unroll
        for (int kf = 0; kf < 2; ++kf) {
          short8 pa = cat8(pfr[m][kf][0], pfr[m][kf][1]);
          short8 vv = cat8(vfr[t2][kf][0], vfr[t2][kf][1]);
          o[m][t2] = __builtin_amdgcn_mfma_f32_16x16x32_bf16(pa, vv, o[m][t2], 0, 0, 0);
        }
      }
    }
  }

  // ---- epilogue ----
  #pragma unroll
  for (int m = 0; m < 2; ++m) {
    #pragma unroll
    for (int t2 = 0; t2 < 4; ++t2) {
      #pragma unroll
      for (int r = 0; r < 4; ++r) {
        float val = o[m][t2][r] / lr[m][r];
        int row = rowg + q0 + m*64 + w*16 + g*4 + r;
        int col = h*64 + t2*16 + ln;
        y[(size_t)row * D_ + col] = f2bf(val);
      }
    }
  }
}

extern "C" void kernel_launch(void* const* d_in, const int* in_sizes, int n_in,
                              void* d_out, int out_size, void* d_ws, size_t ws_size,
                              hipStream_t stream) {
  const float* x    = (const float*)d_in[0];
  const float* Wqkv = (const float*)d_in[1];
  const float* Wout = (const float*)d_in[2];

  ushort* xb    = (ushort*)d_ws;
  ushort* wqkvb = xb    + (size_t)M_ * D_;
  ushort* woutb = wqkvb + (size_t)N1_ * D_;
  ushort* qkvb  = woutb + (size_t)D_ * D_;
  ushort* yb    = qkvb  + (size_t)M_ * N1_;

  cast_f32_bf16<<<1024, 256, 0, stream>>>(x,    xb,    M_ * D_ / 4);
  cast_f32_bf16<<<512,  256, 0, stream>>>(Wqkv, wqkvb, N1_ * D_ / 4);
  cast_f32_bf16<<<256,  256, 0, stream>>>(Wout, woutb, D_ * D_ / 4);

  gemm_bt<1><<<dim3(N1_/128, M_/128), 256, 0, stream>>>(xb, wqkvb, qkvb, M_, N1_, D_);

  attn2<<<dim3(T_/128, B_*H_), 256, 0, stream>>>(qkvb, yb);

  gemm_bt<0><<<dim3(D_/128, M_/128), 256, 0, stream>>>(yb, woutb, d_out, M_, D_, D_);
}

// Round 4
// 208.285 us; speedup vs baseline: 2.4546x; 2.1872x over previous
//
#include <hip/hip_runtime.h>
#include <hip/hip_bf16.h>
#include <stdint.h>

#define B_ 4
#define T_ 2048
#define D_ 1024
#define H_ 16
#define M_ (B_*T_)    // 8192
#define N1_ (3*D_)    // 3072

typedef __attribute__((ext_vector_type(8))) short short8;
typedef __attribute__((ext_vector_type(4))) short short4v;
typedef __attribute__((ext_vector_type(4))) float f32x4;
typedef __attribute__((ext_vector_type(16))) float f32x16;

typedef const __attribute__((address_space(1))) void* as1cp;
typedef __attribute__((address_space(3))) void* as3p;

__device__ __forceinline__ ushort f2bf(float f) {
  union { float f; unsigned u; } v; v.f = f;
  unsigned r = v.u + 0x7fffu + ((v.u >> 16) & 1u);
  return (ushort)(r >> 16);
}

__global__ void cast_f32_bf16(const float* __restrict__ in, ushort* __restrict__ out, int n4) {
  int i = blockIdx.x * blockDim.x + threadIdx.x;
  int stride = gridDim.x * blockDim.x;
  for (; i < n4; i += stride) {
    float4 v = reinterpret_cast<const float4*>(in)[i];
    ushort4 o;
    o.x = f2bf(v.x); o.y = f2bf(v.y); o.z = f2bf(v.z); o.w = f2bf(v.w);
    reinterpret_cast<ushort4*>(out)[i] = o;
  }
}

__device__ __forceinline__ void gload_lds16(const ushort* g, ushort* l) {
  __builtin_amdgcn_global_load_lds((as1cp)(const void*)g, (as3p)(void*)l, 16, 0, 0);
}

__device__ __forceinline__ short4v ds_tr16(unsigned addr) {
  short4v r;
  asm volatile("ds_read_b64_tr_b16 %0, %1" : "=v"(r) : "v"(addr) : "memory");
  return r;
}

__device__ __forceinline__ short8 cat8(short4v a, short4v b) {
  short8 r;
  r[0]=a[0]; r[1]=a[1]; r[2]=a[2]; r[3]=a[3];
  r[4]=b[0]; r[5]=b[1]; r[6]=b[2]; r[7]=b[3];
  return r;
}

__device__ __forceinline__ unsigned cvtpk(float lo, float hi) {
  unsigned r;
  asm("v_cvt_pk_bf16_f32 %0, %1, %2" : "=v"(r) : "v"(lo), "v"(hi));
  return r;
}

__device__ __forceinline__ f32x16 mfma32(short8 a, short8 b, f32x16 c) {
  return __builtin_amdgcn_mfma_f32_32x32x16_bf16(a, b, c, 0, 0, 0);
}

// ---------------- GEMM (unchanged, passing) ----------------
template<int OUT_BF16>
__global__ __launch_bounds__(256) void gemm_bt(const ushort* __restrict__ A,
                                               const ushort* __restrict__ Bm,
                                               void* __restrict__ Cout,
                                               int M, int N, int K) {
  __shared__ ushort Al[128*32];
  __shared__ ushort Bl[128*32];
  const int tid  = threadIdx.x;
  const int lane = tid & 63;
  const int w    = tid >> 6;
  const int g    = lane >> 4;
  const int ln   = lane & 15;
  const int m0 = blockIdx.y * 128;
  const int n0 = blockIdx.x * 128;
  const int wr = w >> 1, wc = w & 1;

  f32x4 acc[4][4] = {};

  for (int kt = 0; kt < K; kt += 32) {
    __syncthreads();
    #pragma unroll
    for (int j = 0; j < 2; ++j) {
      int cc  = w * 2 + j;
      int idx = cc * 64 + lane;
      int row = idx >> 2;
      int kofs = (idx & 3) * 8;
      gload_lds16(A  + (size_t)(m0 + row) * K + kt + kofs, &Al[cc * 512]);
      gload_lds16(Bm + (size_t)(n0 + row) * K + kt + kofs, &Bl[cc * 512]);
    }
    __syncthreads();
    short8 a[4], b[4];
    #pragma unroll
    for (int m = 0; m < 4; ++m)
      a[m] = *(const short8*)&Al[(wr*64 + m*16 + ln) * 32 + g*8];
    #pragma unroll
    for (int n = 0; n < 4; ++n)
      b[n] = *(const short8*)&Bl[(wc*64 + n*16 + ln) * 32 + g*8];
    #pragma unroll
    for (int m = 0; m < 4; ++m)
      #pragma unroll
      for (int n = 0; n < 4; ++n)
        acc[m][n] = __builtin_amdgcn_mfma_f32_16x16x32_bf16(a[m], b[n], acc[m][n], 0, 0, 0);
  }

  #pragma unroll
  for (int m = 0; m < 4; ++m) {
    int gr = m0 + wr*64 + m*16 + g*4;
    #pragma unroll
    for (int n = 0; n < 4; ++n) {
      int gc = n0 + wc*64 + n*16 + ln;
      #pragma unroll
      for (int r = 0; r < 4; ++r) {
        if (OUT_BF16) ((ushort*)Cout)[(size_t)(gr + r) * N + gc] = f2bf(acc[m][n][r]);
        else          ((float*)Cout)[(size_t)(gr + r) * N + gc]  = acc[m][n][r];
      }
    }
  }
}

// ---------------- Flash attention v4: 8 waves x 32 q, swapped 32x32 MFMA ----------------
// P never leaves registers. V staged with the PERMUTED key map so that PV's
// contraction pairs P's natural per-lane key order with matching V rows:
//   k-slot (hi,e)  <->  key = ks*16 + (e&3) + 8*(e>>2) + 4*hi
__global__ __launch_bounds__(512, 2) void attn4(const ushort* __restrict__ qkv,
                                                ushort* __restrict__ y) {
  __shared__ ushort Kl[2][4096];   // [buf][64 keys][64 d], rows 128B, content XOR-swizzled
  __shared__ ushort Vl[2][4096];   // [buf] 64 subtiles of 4x16 bf16 (permuted key map)

  const int tid  = threadIdx.x;
  const int lane = tid & 63;
  const int w    = tid >> 6;
  const int l31  = lane & 31;
  const int hi   = lane >> 5;

  const int bh = blockIdx.x;
  const int b  = bh >> 4;
  const int h  = bh & 15;
  const int qb = 7 - (int)blockIdx.y;       // heavy blocks dispatched first
  const int rowg = b * T_;
  const int q0 = qb * 256;
  const int qw = q0 + w * 32;
  const int qrow = qw + l31;
  const int nt = 4 * qb + 4;

  // K staging coords: row krow, linear byte col (kslot*16), src col XOR-swizzled
  const int krow  = tid >> 3;
  const int kslot = tid & 7;
  const int kcb   = (kslot * 16) ^ ((krow & 7) << 4);
  // V staging coords (PERMUTED key map)
  const int vdh = tid & 1, vr = (tid >> 1) & 3, vg = (tid >> 3) & 3,
            vkq = (tid >> 5) & 1, vks = (tid >> 6) & 3, vdt = (tid >> 8) & 1;
  const int vkey = vks*16 + vkq*8 + (vg >> 1)*4 + vr;
  const int vdd  = vdt*32 + (vg & 1)*16 + vdh*8;

  // Q fragments: B-frag, col=q=l31, k-slot = hi*8+e -> d = kc*16 + hi*8 + e
  short8 qf[4];
  {
    const ushort* qp = qkv + (size_t)(rowg + qrow) * N1_ + h*64 + hi*8;
    #pragma unroll
    for (int kc = 0; kc < 4; ++kc) qf[kc] = *(const short8*)(qp + kc*16);
  }

  f32x16 oacc[2] = {};
  float mrun = -3.0e38f, lrun = 0.f;

  const unsigned VbBase = (unsigned)(size_t)(as3p)(void*)&Vl[0][0];
  const unsigned trln = (unsigned)(((lane >> 4) * 128) + (lane & 15) * 8);

  // prologue: stage tile 0 into buf 0
  {
    gload_lds16(qkv + (size_t)(rowg + 0 + krow) * N1_ + D_ + h*64 + (kcb >> 1), &Kl[0][w*512]);
    gload_lds16(qkv + (size_t)(rowg + 0 + vkey) * N1_ + 2*D_ + h*64 + vdd,      &Vl[0][w*512]);
  }

  for (int kt = 0; kt < nt; ++kt) {
    const int buf = kt & 1;
    const int kbase = kt * 64;
    if (kt + 1 < nt) {
      const int kb2 = kbase + 64;
      gload_lds16(qkv + (size_t)(rowg + kb2 + krow) * N1_ + D_ + h*64 + (kcb >> 1), &Kl[buf^1][w*512]);
      gload_lds16(qkv + (size_t)(rowg + kb2 + vkey) * N1_ + 2*D_ + h*64 + vdd,      &Vl[buf^1][w*512]);
      asm volatile("s_waitcnt vmcnt(2)" ::: "memory");
    } else {
      asm volatile("s_waitcnt vmcnt(0)" ::: "memory");
    }
    asm volatile("s_barrier" ::: "memory");

    const bool act = (kbase <= qw + 31);
    if (act) {
      // ---- QK^T swapped: S^T[key][q] = K x Q ----
      f32x16 sv[2] = {};
      const char* Kb = (const char*)&Kl[buf][0];
      #pragma unroll
      for (int kc = 0; kc < 4; ++kc) {
        unsigned co = (unsigned)((kc*32 + hi*16) ^ ((l31 & 7) << 4));
        short8 k0 = *(const short8*)(Kb + (size_t)l31*128 + co);
        short8 k1 = *(const short8*)(Kb + (size_t)(32 + l31)*128 + co);
        sv[0] = mfma32(k0, qf[kc], sv[0]);
        sv[1] = mfma32(k1, qf[kc], sv[1]);
      }
      // ---- scale + causal mask (log2 domain) ----
      const float Cs = 0.18033688011112042f;   // 0.125 * log2(e)
      if (kbase + 63 > qw) {
        #pragma unroll
        for (int t = 0; t < 2; ++t)
          #pragma unroll
          for (int r = 0; r < 16; ++r) {
            int kl = kbase + t*32 + (r & 3) + 8*(r >> 2) + 4*hi;
            sv[t][r] = (kl > qrow) ? -1.0e38f : sv[t][r] * Cs;
          }
      } else {
        #pragma unroll
        for (int t = 0; t < 2; ++t)
          #pragma unroll
          for (int r = 0; r < 16; ++r) sv[t][r] *= Cs;
      }
      // ---- in-register softmax (cross-half via shfl_xor 32) ----
      float tm[8];
      #pragma unroll
      for (int r = 0; r < 8; ++r)
        tm[r] = fmaxf(fmaxf(sv[0][r], sv[0][r+8]), fmaxf(sv[1][r], sv[1][r+8]));
      float pmax = fmaxf(fmaxf(fmaxf(tm[0], tm[1]), fmaxf(tm[2], tm[3])),
                         fmaxf(fmaxf(tm[4], tm[5]), fmaxf(tm[6], tm[7])));
      pmax = fmaxf(pmax, __shfl_xor(pmax, 32));
      float mnew = fmaxf(mrun, pmax);
      float alpha = exp2f(mrun - mnew);
      mrun = mnew;
      #pragma unroll
      for (int t = 0; t < 2; ++t)
        #pragma unroll
        for (int r = 0; r < 16; ++r) sv[t][r] = exp2f(sv[t][r] - mnew);
      float ts[8];
      #pragma unroll
      for (int r = 0; r < 8; ++r)
        ts[r] = (sv[0][r] + sv[0][r+8]) + (sv[1][r] + sv[1][r+8]);
      float rs = ((ts[0] + ts[1]) + (ts[2] + ts[3])) + ((ts[4] + ts[5]) + (ts[6] + ts[7]));
      rs += __shfl_xor(rs, 32);
      lrun = lrun * alpha + rs;
      #pragma unroll
      for (int r = 0; r < 16; ++r) { oacc[0][r] *= alpha; oacc[1][r] *= alpha; }

      // ---- issue V tr-reads (overlap with P pack) ----
      const unsigned Vb = VbBase + (unsigned)(buf * 8192);
      short4v vt[2][4][2];
      #pragma unroll
      for (int dt = 0; dt < 2; ++dt)
        #pragma unroll
        for (int ks = 0; ks < 4; ++ks) {
          unsigned a = Vb + (unsigned)(dt*4096 + ks*1024) + trln;
          vt[dt][ks][0] = ds_tr16(a);
          vt[dt][ks][1] = ds_tr16(a + 512);
        }

      // ---- pack P in natural key order (no cross-lane moves needed) ----
      short8 pa[4];
      #pragma unroll
      for (int ks = 0; ks < 4; ++ks) {
        const int t = ks >> 1, base = 8 * (ks & 1);
        union { unsigned u[4]; short8 v; } uu;
        uu.u[0] = cvtpk(sv[t][base+0], sv[t][base+1]);
        uu.u[1] = cvtpk(sv[t][base+2], sv[t][base+3]);
        uu.u[2] = cvtpk(sv[t][base+4], sv[t][base+5]);
        uu.u[3] = cvtpk(sv[t][base+6], sv[t][base+7]);
        pa[ks] = uu.v;
      }

      asm volatile("s_waitcnt lgkmcnt(0)" ::: "memory");
      __builtin_amdgcn_sched_barrier(0);
      // ---- PV swapped: O^T[d][q] += V^T x P^T ----
      #pragma unroll
      for (int ks = 0; ks < 4; ++ks) {
        oacc[0] = mfma32(cat8(vt[0][ks][0], vt[0][ks][1]), pa[ks], oacc[0]);
        oacc[1] = mfma32(cat8(vt[1][ks][0], vt[1][ks][1]), pa[ks], oacc[1]);
      }
    }
    asm volatile("s_barrier" ::: "memory");
  }

  // ---- epilogue: O^T regs -> y[q][d] ----
  const float inv = 1.0f / lrun;
  #pragma unroll
  for (int dt = 0; dt < 2; ++dt) {
    #pragma unroll
    for (int rq = 0; rq < 4; ++rq) {
      ushort4 pk4;
      pk4.x = f2bf(oacc[dt][rq*4+0] * inv);
      pk4.y = f2bf(oacc[dt][rq*4+1] * inv);
      pk4.z = f2bf(oacc[dt][rq*4+2] * inv);
      pk4.w = f2bf(oacc[dt][rq*4+3] * inv);
      *(ushort4*)&y[(size_t)(rowg + qrow) * D_ + h*64 + dt*32 + rq*8 + hi*4] = pk4;
    }
  }
}

extern "C" void kernel_launch(void* const* d_in, const int* in_sizes, int n_in,
                              void* d_out, int out_size, void* d_ws, size_t ws_size,
                              hipStream_t stream) {
  const float* x    = (const float*)d_in[0];
  const float* Wqkv = (const float*)d_in[1];
  const float* Wout = (const float*)d_in[2];

  ushort* xb    = (ushort*)d_ws;
  ushort* wqkvb = xb    + (size_t)M_ * D_;
  ushort* woutb = wqkvb + (size_t)N1_ * D_;
  ushort* qkvb  = woutb + (size_t)D_ * D_;
  ushort* yb    = qkvb  + (size_t)M_ * N1_;

  cast_f32_bf16<<<1024, 256, 0, stream>>>(x,    xb,    M_ * D_ / 4);
  cast_f32_bf16<<<512,  256, 0, stream>>>(Wqkv, wqkvb, N1_ * D_ / 4);
  cast_f32_bf16<<<256,  256, 0, stream>>>(Wout, woutb, D_ * D_ / 4);

  gemm_bt<1><<<dim3(N1_/128, M_/128), 256, 0, stream>>>(xb, wqkvb, qkvb, M_, N1_, D_);

  attn4<<<dim3(B_*H_, 8), 512, 0, stream>>>(qkvb, yb);

  gemm_bt<0><<<dim3(D_/128, M_/128), 256, 0, stream>>>(yb, woutb, d_out, M_, D_, D_);
}

// Round 5
// 207.847 us; speedup vs baseline: 2.4598x; 1.0021x over previous
//
#include <hip/hip_runtime.h>
#include <hip/hip_bf16.h>
#include <stdint.h>

#define B_ 4
#define T_ 2048
#define D_ 1024
#define H_ 16
#define M_ (B_*T_)    // 8192
#define N1_ (3*D_)    // 3072

typedef __attribute__((ext_vector_type(8))) short short8;
typedef __attribute__((ext_vector_type(4))) short short4v;
typedef __attribute__((ext_vector_type(4))) float f32x4;
typedef __attribute__((ext_vector_type(16))) float f32x16;

typedef const __attribute__((address_space(1))) void* as1cp;
typedef __attribute__((address_space(3))) void* as3p;

__device__ __forceinline__ ushort f2bf(float f) {
  union { float f; unsigned u; } v; v.f = f;
  unsigned r = v.u + 0x7fffu + ((v.u >> 16) & 1u);
  return (ushort)(r >> 16);
}

__global__ void cast_f32_bf16(const float* __restrict__ in, ushort* __restrict__ out, int n4) {
  int i = blockIdx.x * blockDim.x + threadIdx.x;
  int stride = gridDim.x * blockDim.x;
  for (; i < n4; i += stride) {
    float4 v = reinterpret_cast<const float4*>(in)[i];
    ushort4 o;
    o.x = f2bf(v.x); o.y = f2bf(v.y); o.z = f2bf(v.z); o.w = f2bf(v.w);
    reinterpret_cast<ushort4*>(out)[i] = o;
  }
}

__device__ __forceinline__ void gload_lds16(const ushort* g, ushort* l) {
  __builtin_amdgcn_global_load_lds((as1cp)(const void*)g, (as3p)(void*)l, 16, 0, 0);
}

__device__ __forceinline__ short4v ds_tr16(unsigned addr) {
  short4v r;
  asm volatile("ds_read_b64_tr_b16 %0, %1" : "=v"(r) : "v"(addr) : "memory");
  return r;
}

__device__ __forceinline__ short8 cat8(short4v a, short4v b) {
  short8 r;
  r[0]=a[0]; r[1]=a[1]; r[2]=a[2]; r[3]=a[3];
  r[4]=b[0]; r[5]=b[1]; r[6]=b[2]; r[7]=b[3];
  return r;
}

__device__ __forceinline__ unsigned cvtpk(float lo, float hi) {
  unsigned r;
  asm("v_cvt_pk_bf16_f32 %0, %1, %2" : "=v"(r) : "v"(lo), "v"(hi));
  return r;
}

__device__ __forceinline__ f32x16 mfma32(short8 a, short8 b, f32x16 c) {
  return __builtin_amdgcn_mfma_f32_32x32x16_bf16(a, b, c, 0, 0, 0);
}

// ---------------- GEMM (unchanged, passing) ----------------
template<int OUT_BF16>
__global__ __launch_bounds__(256) void gemm_bt(const ushort* __restrict__ A,
                                               const ushort* __restrict__ Bm,
                                               void* __restrict__ Cout,
                                               int M, int N, int K) {
  __shared__ ushort Al[128*32];
  __shared__ ushort Bl[128*32];
  const int tid  = threadIdx.x;
  const int lane = tid & 63;
  const int w    = tid >> 6;
  const int g    = lane >> 4;
  const int ln   = lane & 15;
  const int m0 = blockIdx.y * 128;
  const int n0 = blockIdx.x * 128;
  const int wr = w >> 1, wc = w & 1;

  f32x4 acc[4][4] = {};

  for (int kt = 0; kt < K; kt += 32) {
    __syncthreads();
    #pragma unroll
    for (int j = 0; j < 2; ++j) {
      int cc  = w * 2 + j;
      int idx = cc * 64 + lane;
      int row = idx >> 2;
      int kofs = (idx & 3) * 8;
      gload_lds16(A  + (size_t)(m0 + row) * K + kt + kofs, &Al[cc * 512]);
      gload_lds16(Bm + (size_t)(n0 + row) * K + kt + kofs, &Bl[cc * 512]);
    }
    __syncthreads();
    short8 a[4], b[4];
    #pragma unroll
    for (int m = 0; m < 4; ++m)
      a[m] = *(const short8*)&Al[(wr*64 + m*16 + ln) * 32 + g*8];
    #pragma unroll
    for (int n = 0; n < 4; ++n)
      b[n] = *(const short8*)&Bl[(wc*64 + n*16 + ln) * 32 + g*8];
    #pragma unroll
    for (int m = 0; m < 4; ++m)
      #pragma unroll
      for (int n = 0; n < 4; ++n)
        acc[m][n] = __builtin_amdgcn_mfma_f32_16x16x32_bf16(a[m], b[n], acc[m][n], 0, 0, 0);
  }

  #pragma unroll
  for (int m = 0; m < 4; ++m) {
    int gr = m0 + wr*64 + m*16 + g*4;
    #pragma unroll
    for (int n = 0; n < 4; ++n) {
      int gc = n0 + wc*64 + n*16 + ln;
      #pragma unroll
      for (int r = 0; r < 4; ++r) {
        if (OUT_BF16) ((ushort*)Cout)[(size_t)(gr + r) * N + gc] = f2bf(acc[m][n][r]);
        else          ((float*)Cout)[(size_t)(gr + r) * N + gc]  = acc[m][n][r];
      }
    }
  }
}

// ---------------- Flash attention v5: causal-balanced pairs + defer-max ----------------
// Block (bh, y) handles q-ranges qA=y and qB=7-y; one kt loop stages K/V once,
// both ranges consume the staged tile (actA implies actB). 256 blocks = 1/CU,
// every block does identical total work (36 tile-units).
__global__ __launch_bounds__(512, 2) void attn5(const ushort* __restrict__ qkv,
                                                ushort* __restrict__ y) {
  __shared__ ushort Kl[2][4096];   // [buf][64 keys][64 d], rows 128B, content XOR-swizzled
  __shared__ ushort Vl[2][4096];   // [buf] 64 subtiles of 4x16 bf16 (permuted key map)

  const int tid  = threadIdx.x;
  const int lane = tid & 63;
  const int w    = tid >> 6;
  const int l31  = lane & 31;
  const int hi   = lane >> 5;

  const int bh = blockIdx.x;
  const int b  = bh >> 4;
  const int h  = bh & 15;
  const int rowg = b * T_;
  const int qA = (int)blockIdx.y;       // 0..3  (light range)
  const int qB = 7 - qA;                // 7..4  (heavy range)
  const int qwA = qA * 256 + w * 32;
  const int qwB = qB * 256 + w * 32;
  const int qrowA = qwA + l31;
  const int qrowB = qwB + l31;
  const int nt = 4 * qB + 4;

  // K staging coords: row krow, linear byte col (kslot*16), src col XOR-swizzled
  const int krow  = tid >> 3;
  const int kslot = tid & 7;
  const int kcb   = (kslot * 16) ^ ((krow & 7) << 4);
  // V staging coords (PERMUTED key map matching P's natural per-lane key order)
  const int vdh = tid & 1, vr = (tid >> 1) & 3, vg = (tid >> 3) & 3,
            vkq = (tid >> 5) & 1, vks = (tid >> 6) & 3, vdt = (tid >> 8) & 1;
  const int vkey = vks*16 + vkq*8 + (vg >> 1)*4 + vr;
  const int vdd  = vdt*32 + (vg & 1)*16 + vdh*8;

  // Q fragments for both ranges
  short8 qfA[4], qfB[4];
  {
    const ushort* qpA = qkv + (size_t)(rowg + qrowA) * N1_ + h*64 + hi*8;
    const ushort* qpB = qkv + (size_t)(rowg + qrowB) * N1_ + h*64 + hi*8;
    #pragma unroll
    for (int kc = 0; kc < 4; ++kc) {
      qfA[kc] = *(const short8*)(qpA + kc*16);
      qfB[kc] = *(const short8*)(qpB + kc*16);
    }
  }

  f32x16 oA[2] = {}, oB[2] = {};
  float mA = -3.0e38f, lA = 0.f, mB = -3.0e38f, lB = 0.f;

  const unsigned VbBase = (unsigned)(size_t)(as3p)(void*)&Vl[0][0];
  const unsigned trln = (unsigned)(((lane >> 4) * 128) + (lane & 15) * 8);

  // per-tile body for one q-range
  auto process = [&](int kbase, int buf, int qw_, int qrow_,
                     const short8* qf_, f32x16* o_, float& m_, float& l_) {
    // ---- QK^T swapped: S^T[key][q] = K x Q ----
    f32x16 sv[2] = {};
    const char* Kb = (const char*)&Kl[buf][0];
    __builtin_amdgcn_s_setprio(1);
    #pragma unroll
    for (int kc = 0; kc < 4; ++kc) {
      unsigned co = (unsigned)((kc*32 + hi*16) ^ ((l31 & 7) << 4));
      short8 k0 = *(const short8*)(Kb + (size_t)l31*128 + co);
      short8 k1 = *(const short8*)(Kb + (size_t)(32 + l31)*128 + co);
      sv[0] = mfma32(k0, qf_[kc], sv[0]);
      sv[1] = mfma32(k1, qf_[kc], sv[1]);
    }
    __builtin_amdgcn_s_setprio(0);
    // ---- scale + causal mask (log2 domain) ----
    const float Cs = 0.18033688011112042f;   // 0.125 * log2(e)
    if (kbase + 63 > qw_) {
      #pragma unroll
      for (int t = 0; t < 2; ++t)
        #pragma unroll
        for (int r = 0; r < 16; ++r) {
          int kl = kbase + t*32 + (r & 3) + 8*(r >> 2) + 4*hi;
          sv[t][r] = (kl > qrow_) ? -1.0e38f : sv[t][r] * Cs;
        }
    } else {
      #pragma unroll
      for (int t = 0; t < 2; ++t)
        #pragma unroll
        for (int r = 0; r < 16; ++r) sv[t][r] *= Cs;
    }
    // ---- in-register softmax with defer-max (T13) ----
    float tm[8];
    #pragma unroll
    for (int r = 0; r < 8; ++r)
      tm[r] = fmaxf(fmaxf(sv[0][r], sv[0][r+8]), fmaxf(sv[1][r], sv[1][r+8]));
    float pmax = fmaxf(fmaxf(fmaxf(tm[0], tm[1]), fmaxf(tm[2], tm[3])),
                       fmaxf(fmaxf(tm[4], tm[5]), fmaxf(tm[6], tm[7])));
    pmax = fmaxf(pmax, __shfl_xor(pmax, 32));
    if (!__all(pmax <= m_ + 8.0f)) {
      float mnew = fmaxf(m_, pmax);
      float alpha = exp2f(m_ - mnew);
      m_ = mnew;
      l_ *= alpha;
      #pragma unroll
      for (int r = 0; r < 16; ++r) { o_[0][r] *= alpha; o_[1][r] *= alpha; }
    }
    #pragma unroll
    for (int t = 0; t < 2; ++t)
      #pragma unroll
      for (int r = 0; r < 16; ++r) sv[t][r] = exp2f(sv[t][r] - m_);
    float ts[8];
    #pragma unroll
    for (int r = 0; r < 8; ++r)
      ts[r] = (sv[0][r] + sv[0][r+8]) + (sv[1][r] + sv[1][r+8]);
    float rs = ((ts[0] + ts[1]) + (ts[2] + ts[3])) + ((ts[4] + ts[5]) + (ts[6] + ts[7]));
    rs += __shfl_xor(rs, 32);
    l_ += rs;

    // ---- issue V tr-reads (overlap with P pack) ----
    const unsigned Vb = VbBase + (unsigned)(buf * 8192);
    short4v vt[2][4][2];
    #pragma unroll
    for (int dt = 0; dt < 2; ++dt)
      #pragma unroll
      for (int ks = 0; ks < 4; ++ks) {
        unsigned a = Vb + (unsigned)(dt*4096 + ks*1024) + trln;
        vt[dt][ks][0] = ds_tr16(a);
        vt[dt][ks][1] = ds_tr16(a + 512);
      }

    // ---- pack P in natural key order ----
    short8 pa[4];
    #pragma unroll
    for (int ks = 0; ks < 4; ++ks) {
      const int t = ks >> 1, base = 8 * (ks & 1);
      union { unsigned u[4]; short8 v; } uu;
      uu.u[0] = cvtpk(sv[t][base+0], sv[t][base+1]);
      uu.u[1] = cvtpk(sv[t][base+2], sv[t][base+3]);
      uu.u[2] = cvtpk(sv[t][base+4], sv[t][base+5]);
      uu.u[3] = cvtpk(sv[t][base+6], sv[t][base+7]);
      pa[ks] = uu.v;
    }

    asm volatile("s_waitcnt lgkmcnt(0)" ::: "memory");
    __builtin_amdgcn_sched_barrier(0);
    // ---- PV swapped: O^T[d][q] += V^T x P^T ----
    __builtin_amdgcn_s_setprio(1);
    #pragma unroll
    for (int ks = 0; ks < 4; ++ks) {
      o_[0] = mfma32(cat8(vt[0][ks][0], vt[0][ks][1]), pa[ks], o_[0]);
      o_[1] = mfma32(cat8(vt[1][ks][0], vt[1][ks][1]), pa[ks], o_[1]);
    }
    __builtin_amdgcn_s_setprio(0);
  };

  // prologue: stage tile 0 into buf 0
  gload_lds16(qkv + (size_t)(rowg + 0 + krow) * N1_ + D_ + h*64 + (kcb >> 1), &Kl[0][w*512]);
  gload_lds16(qkv + (size_t)(rowg + 0 + vkey) * N1_ + 2*D_ + h*64 + vdd,      &Vl[0][w*512]);

  for (int kt = 0; kt < nt; ++kt) {
    const int buf = kt & 1;
    const int kbase = kt * 64;
    if (kt + 1 < nt) {
      const int kb2 = kbase + 64;
      gload_lds16(qkv + (size_t)(rowg + kb2 + krow) * N1_ + D_ + h*64 + (kcb >> 1), &Kl[buf^1][w*512]);
      gload_lds16(qkv + (size_t)(rowg + kb2 + vkey) * N1_ + 2*D_ + h*64 + vdd,      &Vl[buf^1][w*512]);
      asm volatile("s_waitcnt vmcnt(2)" ::: "memory");
    } else {
      asm volatile("s_waitcnt vmcnt(0)" ::: "memory");
    }
    asm volatile("s_barrier" ::: "memory");

    if (kbase <= qwB + 31) process(kbase, buf, qwB, qrowB, qfB, oB, mB, lB);
    if (kbase <= qwA + 31) process(kbase, buf, qwA, qrowA, qfA, oA, mA, lA);

    asm volatile("s_barrier" ::: "memory");
  }

  // ---- epilogue: O^T regs -> y[q][d] for both ranges ----
  const float invA = 1.0f / lA, invB = 1.0f / lB;
  #pragma unroll
  for (int dt = 0; dt < 2; ++dt) {
    #pragma unroll
    for (int rq = 0; rq < 4; ++rq) {
      ushort4 pk4;
      pk4.x = f2bf(oB[dt][rq*4+0] * invB);
      pk4.y = f2bf(oB[dt][rq*4+1] * invB);
      pk4.z = f2bf(oB[dt][rq*4+2] * invB);
      pk4.w = f2bf(oB[dt][rq*4+3] * invB);
      *(ushort4*)&y[(size_t)(rowg + qrowB) * D_ + h*64 + dt*32 + rq*8 + hi*4] = pk4;
      pk4.x = f2bf(oA[dt][rq*4+0] * invA);
      pk4.y = f2bf(oA[dt][rq*4+1] * invA);
      pk4.z = f2bf(oA[dt][rq*4+2] * invA);
      pk4.w = f2bf(oA[dt][rq*4+3] * invA);
      *(ushort4*)&y[(size_t)(rowg + qrowA) * D_ + h*64 + dt*32 + rq*8 + hi*4] = pk4;
    }
  }
}

extern "C" void kernel_launch(void* const* d_in, const int* in_sizes, int n_in,
                              void* d_out, int out_size, void* d_ws, size_t ws_size,
                              hipStream_t stream) {
  const float* x    = (const float*)d_in[0];
  const float* Wqkv = (const float*)d_in[1];
  const float* Wout = (const float*)d_in[2];

  ushort* xb    = (ushort*)d_ws;
  ushort* wqkvb = xb    + (size_t)M_ * D_;
  ushort* woutb = wqkvb + (size_t)N1_ * D_;
  ushort* qkvb  = woutb + (size_t)D_ * D_;
  ushort* yb    = qkvb  + (size_t)M_ * N1_;

  cast_f32_bf16<<<1024, 256, 0, stream>>>(x,    xb,    M_ * D_ / 4);
  cast_f32_bf16<<<512,  256, 0, stream>>>(Wqkv, wqkvb, N1_ * D_ / 4);
  cast_f32_bf16<<<256,  256, 0, stream>>>(Wout, woutb, D_ * D_ / 4);

  gemm_bt<1><<<dim3(N1_/128, M_/128), 256, 0, stream>>>(xb, wqkvb, qkvb, M_, N1_, D_);

  attn5<<<dim3(B_*H_, 4), 512, 0, stream>>>(qkvb, yb);

  gemm_bt<0><<<dim3(D_/128, M_/128), 256, 0, stream>>>(yb, woutb, d_out, M_, D_, D_);
}